// Round 16
// baseline (152.315 us; speedup 1.0000x reference)
//
#include <hip/hip_runtime.h>

#define NROWS 65536
#define EDIM 256
#define NQ 8
#define NE 512
#define DSUB 32
#define RPB 128           // rows per screen block (2 row-groups of 16 per wave)
#define NRG 2             // row-groups per wave
#define RPB_FB 64         // fallback kernel rows per block
#define MARGIN 1e-4f      // fallback kernel margin (r4-proven)
#define SM_ACC 7.5e-5f    // acc-scale screen margin (quant 3.05e-5 + 2*eps 2e-5)
#define KEYMASK 0xFFFFFE00u

typedef __attribute__((ext_vector_type(8))) short short8;
typedef __attribute__((ext_vector_type(4))) float f32x4;

// round-to-nearest-even f32 -> bf16 (bit-exact, deterministic)
static __device__ __forceinline__ unsigned short bf16_rne(float f) {
  unsigned int u = __float_as_uint(f);
  unsigned int r = 0x7FFFu + ((u >> 16) & 1u);
  return (unsigned short)((u + r) >> 16);
}
static __device__ __forceinline__ float bf16_f32(unsigned short h) {
  return __uint_as_float(((unsigned int)h) << 16);
}
static __device__ __forceinline__ unsigned int umed3(unsigned int a,
                                                     unsigned int b,
                                                     unsigned int c) {
  unsigned int d;
  asm("v_med3_u32 %0, %1, %2, %3" : "=v"(d) : "v"(a), "v"(b), "v"(c));
  return d;
}

// ===== numpy float32 bit-exact building blocks (validated rounds 3-15) =====
__device__ __forceinline__ float np_pairwise32(const float* p) {
  float r0 = p[0], r1 = p[1], r2 = p[2], r3 = p[3];
  float r4 = p[4], r5 = p[5], r6 = p[6], r7 = p[7];
  r0 = __fadd_rn(r0, p[8]);  r1 = __fadd_rn(r1, p[9]);
  r2 = __fadd_rn(r2, p[10]); r3 = __fadd_rn(r3, p[11]);
  r4 = __fadd_rn(r4, p[12]); r5 = __fadd_rn(r5, p[13]);
  r6 = __fadd_rn(r6, p[14]); r7 = __fadd_rn(r7, p[15]);
  r0 = __fadd_rn(r0, p[16]); r1 = __fadd_rn(r1, p[17]);
  r2 = __fadd_rn(r2, p[18]); r3 = __fadd_rn(r3, p[19]);
  r4 = __fadd_rn(r4, p[20]); r5 = __fadd_rn(r5, p[21]);
  r6 = __fadd_rn(r6, p[22]); r7 = __fadd_rn(r7, p[23]);
  r0 = __fadd_rn(r0, p[24]); r1 = __fadd_rn(r1, p[25]);
  r2 = __fadd_rn(r2, p[26]); r3 = __fadd_rn(r3, p[27]);
  r4 = __fadd_rn(r4, p[28]); r5 = __fadd_rn(r5, p[29]);
  r6 = __fadd_rn(r6, p[30]); r7 = __fadd_rn(r7, p[31]);
  float a = __fadd_rn(__fadd_rn(r0, r1), __fadd_rn(r2, r3));
  float b = __fadd_rn(__fadd_rn(r4, r5), __fadd_rn(r6, r7));
  return __fadd_rn(a, b);
}

// numpy pairwise ||z||^2, blockwise float4 (r6-proven order-preserving form)
__device__ __forceinline__ float np_znorm32(const float* zrow) {
  float r0, r1, r2, r3, r4, r5, r6, r7;
  float4 za = *(const float4*)&zrow[0];
  float4 zb = *(const float4*)&zrow[4];
  r0 = __fmul_rn(za.x, za.x); r1 = __fmul_rn(za.y, za.y);
  r2 = __fmul_rn(za.z, za.z); r3 = __fmul_rn(za.w, za.w);
  r4 = __fmul_rn(zb.x, zb.x); r5 = __fmul_rn(zb.y, zb.y);
  r6 = __fmul_rn(zb.z, zb.z); r7 = __fmul_rn(zb.w, zb.w);
  #pragma unroll
  for (int b = 1; b < 4; ++b) {
    za = *(const float4*)&zrow[b * 8];
    zb = *(const float4*)&zrow[b * 8 + 4];
    r0 = __fadd_rn(r0, __fmul_rn(za.x, za.x));
    r1 = __fadd_rn(r1, __fmul_rn(za.y, za.y));
    r2 = __fadd_rn(r2, __fmul_rn(za.z, za.z));
    r3 = __fadd_rn(r3, __fmul_rn(za.w, za.w));
    r4 = __fadd_rn(r4, __fmul_rn(zb.x, zb.x));
    r5 = __fadd_rn(r5, __fmul_rn(zb.y, zb.y));
    r6 = __fadd_rn(r6, __fmul_rn(zb.z, zb.z));
    r7 = __fadd_rn(r7, __fmul_rn(zb.w, zb.w));
  }
  float aa = __fadd_rn(__fadd_rn(r0, r1), __fadd_rn(r2, r3));
  float bb = __fadd_rn(__fadd_rn(r4, r5), __fadd_rn(r6, r7));
  return __fadd_rn(aa, bb);
}

// numpy einsum f32 dot over 32 dims (SSE blocks in order 3,2,1,0,7,6,5,4)
__device__ __forceinline__ float np_dot32(const float4* cp, const float* zrow) {
  float a0 = 0.f, a1 = 0.f, a2 = 0.f, a3 = 0.f;
  const int border[8] = {3, 2, 1, 0, 7, 6, 5, 4};
  #pragma unroll
  for (int bi = 0; bi < 8; ++bi) {
    int b = border[bi];
    float4 cv = cp[b];
    float4 zv = *(const float4*)&zrow[b * 4];
    a0 = __fadd_rn(__fmul_rn(cv.x, zv.x), a0);
    a1 = __fadd_rn(__fmul_rn(cv.y, zv.y), a1);
    a2 = __fadd_rn(__fmul_rn(cv.z, zv.z), a2);
    a3 = __fadd_rn(__fmul_rn(cv.w, zv.w), a3);
  }
  return __fadd_rn(__fadd_rn(a0, a1), __fadd_rn(a2, a3));
}

// exact numpy d2 for one (row, code)
__device__ __forceinline__ float np_d2(const float* __restrict__ cb,
                                       const float* __restrict__ cnorm,
                                       int q, int k, const float* zrow, float A) {
  const float4* cp = (const float4*)(cb + ((size_t)(q * NE + k)) * DSUB);
  float e = np_dot32(cp, zrow);
  return __fsub_rn(__fadd_rn(A, cnorm[q * NE + k]), __fadd_rn(e, e));
}

// ===== per-code squared norm (numpy semantics) + MFMA seed copy (-> ws) =====
__global__ void vq_cnorm_kernel(const float* __restrict__ cb,
                                float* __restrict__ cnorm,
                                float* __restrict__ cnh) {
  int q = blockIdx.x;
  for (int k = threadIdx.x; k < NE; k += blockDim.x) {
    const float* c = cb + ((size_t)(q * NE + k)) * DSUB;
    float p[DSUB];
    #pragma unroll
    for (int d = 0; d < DSUB; ++d) p[d] = __fmul_rn(c[d], c[d]);
    float s = np_pairwise32(p);
    cnorm[q * NE + k] = s;
    // MFMA accumulator seed: -(cn+1)/2  => acc = dot - (cn+1)/2, always < 0
    cnh[q * NE + k] = __fmul_rn(__fadd_rn(s, 1.0f), -0.5f);
  }
}

// ===== pre-split codebook to bf16 hi/lo planes, code-major (-> ws) =====
// cbh/cbl layout == cb layout: [q][code][d] contiguous (hi / lo plane)
__global__ void vq_split_kernel(const float* __restrict__ cb,
                                unsigned short* __restrict__ cbh,
                                unsigned short* __restrict__ cbl) {
  int i = blockIdx.x * 256 + threadIdx.x;    // 0..131071 = (q*512+k)*32+d
  float v = cb[i];
  unsigned short hh = bf16_rne(v);
  unsigned short ll = bf16_rne(__fsub_rn(v, bf16_f32(hh)));
  cbh[i] = hh;
  cbl[i] = ll;
}

// ===== stage A: MFMA screen, LDS-free / barrier-free =====
// B-fragments + seeds loaded directly global->reg (L2-resident per-q planes),
// 1-deep manual prefetch. Numerically identical to r14's passing screen.
// res[n*8+q] = flag3<<31 | flag2<<30 | i2<<9 | i1
__global__ __launch_bounds__(256) void vq_screen_kernel(
    const float* __restrict__ z, const unsigned short* __restrict__ cbh,
    const unsigned short* __restrict__ cbl,
    const float* __restrict__ cnh, unsigned int* __restrict__ res) {
  const int q    = blockIdx.y;
  const int row0 = blockIdx.x * RPB;
  const int tid  = threadIdx.x;
  const int w    = tid >> 6;
  const int lane = tid & 63;
  const int g    = lane >> 4;
  const int c16  = lane & 15;

  // per-lane base pointers into this q's planes (lane reads code c16 + 16*ct)
  const unsigned short* bhp = cbh + (size_t)q * NE * DSUB + c16 * DSUB + g * 8;
  const unsigned short* blp = cbl + (size_t)q * NE * DSUB + c16 * DSUB + g * 8;
  const float* cnp = cnh + q * NE + c16;

  // A fragments: direct global->reg (each thread's own NRG x 8 z values)
  short8 ah[NRG], al[NRG];
  #pragma unroll
  for (int rg = 0; rg < NRG; ++rg) {
    const float* zp = z + (size_t)(row0 + w * (16 * NRG) + rg * 16 + c16) * EDIM
                        + q * DSUB + g * 8;
    float zr8[8];
    *(float4*)&zr8[0] = *(const float4*)&zp[0];
    *(float4*)&zr8[4] = *(const float4*)&zp[4];
    short8 h, l;
    #pragma unroll
    for (int i = 0; i < 8; ++i) {
      unsigned short hh = bf16_rne(zr8[i]);
      unsigned short ll = bf16_rne(__fsub_rn(zr8[i], bf16_f32(hh)));
      h[i] = (short)hh;
      l[i] = (short)ll;
    }
    ah[rg] = h;
    al[rg] = l;
  }

  // packed-key sorted triples per (rg, j): k1 <= k2 <= k3 (unsigned best-first;
  // acc always negative: smaller unsigned = larger acc = smaller d2)
  unsigned int k1[NRG][4], k2[NRG][4], k3[NRG][4];
  #pragma unroll
  for (int rg = 0; rg < NRG; ++rg)
    #pragma unroll
    for (int j = 0; j < 4; ++j) {
      k1[rg][j] = 0xFFFFFFFFu; k2[rg][j] = 0xFFFFFFFFu; k3[rg][j] = 0xFFFFFFFFu;
    }

  // 1-deep prefetch pipeline over 32 code-tiles (no LDS, no barriers)
  short8 bh = *(const short8*)bhp;
  short8 bl = *(const short8*)blp;
  float seed = *cnp;

  #pragma unroll 1
  for (int ct = 0; ct < 32; ++ct) {
    int ctn = (ct < 31) ? ct + 1 : 31;
    short8 bhn = *(const short8*)(bhp + (size_t)ctn * 16 * DSUB);
    short8 bln = *(const short8*)(blp + (size_t)ctn * 16 * DSUB);
    float seedn = cnp[ctn * 16];

    int code = ct * 16 + c16;
    #pragma unroll
    for (int rg = 0; rg < NRG; ++rg) {
      f32x4 acc = {seed, seed, seed, seed};  // acc = dot - (cn+1)/2 after MFMAs
      acc = __builtin_amdgcn_mfma_f32_16x16x32_bf16(ah[rg], bh, acc, 0, 0, 0);
      acc = __builtin_amdgcn_mfma_f32_16x16x32_bf16(al[rg], bh, acc, 0, 0, 0);
      acc = __builtin_amdgcn_mfma_f32_16x16x32_bf16(ah[rg], bl, acc, 0, 0, 0);
      #pragma unroll
      for (int j = 0; j < 4; ++j) {
        unsigned int key = (__float_as_uint(acc[j]) & KEYMASK) | (unsigned int)code;
        k3[rg][j] = umed3(k2[rg][j], k3[rg][j], key);
        k2[rg][j] = umed3(k1[rg][j], k2[rg][j], key);
        k1[rg][j] = min(k1[rg][j], key);
      }
    }
    bh = bhn; bl = bln; seed = seedn;
  }

  // cross-lane merge of sorted triples within each 16-lane group
  #pragma unroll
  for (int off = 1; off <= 8; off <<= 1) {
    #pragma unroll
    for (int rg = 0; rg < NRG; ++rg)
      #pragma unroll
      for (int j = 0; j < 4; ++j) {
        unsigned int a1 = k1[rg][j], a2 = k2[rg][j], a3 = k3[rg][j];
        unsigned int b1 = (unsigned int)__shfl_xor((int)a1, off);
        unsigned int b2 = (unsigned int)__shfl_xor((int)a2, off);
        unsigned int b3 = (unsigned int)__shfl_xor((int)a3, off);
        unsigned int lo1 = min(a1, b1), hi1 = max(a1, b1);
        unsigned int lo2 = min(a2, b2), hi2 = max(a2, b2);
        unsigned int lo3 = min(a3, b3);
        k1[rg][j] = lo1;
        k2[rg][j] = min(hi1, lo2);
        k3[rg][j] = min(max(hi1, lo2), min(hi2, lo3));
      }
  }
  #pragma unroll
  for (int rg = 0; rg < NRG; ++rg)
    #pragma unroll
    for (int j = 0; j < 4; ++j) {
      if (c16 == j) {
        float b1 = __uint_as_float(k1[rg][j] & KEYMASK);
        float b2 = __uint_as_float(k2[rg][j] & KEYMASK);
        float b3 = __uint_as_float(k3[rg][j] & KEYMASK);
        unsigned int u = (k1[rg][j] & 511u) | ((k2[rg][j] & 511u) << 9);
        if (__fsub_rn(b1, b2) <= SM_ACC) u |= (1u << 30);
        if (__fsub_rn(b1, b3) <= SM_ACC) u |= (1u << 31);
        res[(size_t)(row0 + w * (16 * NRG) + rg * 16 + g * 4 + j) * NQ + q] = u;
      }
    }
}

// ===== stage B: gather + inline exact resolve + loss partials (r11) =====
__global__ __launch_bounds__(256) void vq_gather_kernel(
    const float* __restrict__ z, const float* __restrict__ cb,
    const float* __restrict__ cnorm, const unsigned int* __restrict__ res,
    float* __restrict__ out_zq, float* __restrict__ out_idx,
    float* __restrict__ partials) {
  __shared__ double s_part[4];
  const int e = blockIdx.x * 256 + threadIdx.x;
  const int n = e >> 3, q = e & 7;
  const int lane = threadIdx.x & 63;
  unsigned int u = res[e];
  int k = (int)(u & 511u);
  const float* zrow = z + (size_t)n * EDIM + q * DSUB;

  // 2-candidate exact numpy resolve (flag2 && !flag3)
  if ((u & 0x40000000u) && !(u & 0x80000000u)) {
    int k2 = (int)((u >> 9) & 511u);
    float A = np_znorm32(zrow);
    float d1 = np_d2(cb, cnorm, q, k,  zrow, A);
    float d2 = np_d2(cb, cnorm, q, k2, zrow, A);
    if (d2 < d1 || (d2 == d1 && k2 < k)) k = k2;
  }

  // rare flag3: wave-cooperative full numpy-exact rescan
  unsigned long long m = __ballot((u >> 31) & 1u);
  while (m) {
    int src = (int)__builtin_ctzll(m);
    m &= m - 1;
    int ee = blockIdx.x * 256 + (int)(threadIdx.x & ~63u) + src;  // wave-uniform
    int nn = ee >> 3, qq = ee & 7;
    const float* zr2 = z + (size_t)nn * EDIM + qq * DSUB;
    float A = np_znorm32(zr2);
    float bv = 1e30f; int bk = 0x7FFFFFFF;
    #pragma unroll 2
    for (int i = 0; i < 8; ++i) {
      int kk = lane * 8 + i;
      float d2 = np_d2(cb, cnorm, qq, kk, zr2, A);
      if (d2 < bv) { bv = d2; bk = kk; }     // ascending kk keeps lowest on tie
    }
    #pragma unroll
    for (int off = 1; off <= 32; off <<= 1) {
      float ov = __shfl_xor(bv, off);
      int   ok = __shfl_xor(bk, off);
      if (ov < bv || (ov == bv && ok < bk)) { bv = ov; bk = ok; }
    }
    if (lane == src) k = bk;
  }

  // outputs + f64 loss partial
  const float4* cp = (const float4*)(cb + ((size_t)(q * NE + k)) * DSUB);
  const float4* zp = (const float4*)zrow;
  float4* op = (float4*)(out_zq + (size_t)n * EDIM + q * DSUB);
  double lacc = 0.0;
  #pragma unroll
  for (int j = 0; j < 8; ++j) {
    float4 cv = cp[j];
    float4 zv = zp[j];
    op[j] = cv;
    double d0 = (double)cv.x - (double)zv.x;
    double d1 = (double)cv.y - (double)zv.y;
    double d2 = (double)cv.z - (double)zv.z;
    double d3 = (double)cv.w - (double)zv.w;
    lacc = fma(d0, d0, lacc); lacc = fma(d1, d1, lacc);
    lacc = fma(d2, d2, lacc); lacc = fma(d3, d3, lacc);
  }
  out_idx[e] = (float)k;

  const int w = threadIdx.x >> 6;
  #pragma unroll
  for (int off = 1; off < 64; off <<= 1) lacc += __shfl_xor(lacc, off);
  if (lane == 0) s_part[w] = lacc;
  __syncthreads();
  if (threadIdx.x == 0)
    partials[blockIdx.x] = (float)(s_part[0] + s_part[1] + s_part[2] + s_part[3]);
}

__global__ void vq_loss_kernel(const float* __restrict__ partials, int np,
                               float* __restrict__ out_loss) {
  __shared__ double sh[256];
  double s = 0.0;
  for (int i = threadIdx.x; i < np; i += 256) s += (double)partials[i];
  sh[threadIdx.x] = s;
  __syncthreads();
  for (int st = 128; st > 0; st >>= 1) {
    if ((int)threadIdx.x < st) sh[threadIdx.x] += sh[threadIdx.x + st];
    __syncthreads();
  }
  if (threadIdx.x == 0) {
    double m = sh[0] / 16777216.0;      // mean over 8*65536*32 elements
    *out_loss = (float)(1.25 * m);      // BETA*m + m
  }
}

// ===== fallback (round-4-style single kernel, known-passing) =====
__global__ __launch_bounds__(256) void vq_mfma_fb_kernel(
    const float* __restrict__ z, const float* __restrict__ cb,
    const float* __restrict__ cnorm,
    float* __restrict__ out_zq, float* __restrict__ out_idx,
    float* __restrict__ partials) {
  __shared__ unsigned short s_cb[2][4][NE][8];
  __shared__ float s_z[RPB_FB][DSUB];
  __shared__ float s_cn[NE];
  __shared__ unsigned int s_res[4][16];
  __shared__ double s_part[4];

  const int q    = blockIdx.y;
  const int row0 = blockIdx.x * RPB_FB;
  const int tid  = threadIdx.x;
  const int w    = tid >> 6;
  const int lane = tid & 63;
  const int g    = lane >> 4;
  const int c16  = lane & 15;

  {
    const float4* cbq = (const float4*)(cb + (size_t)q * NE * DSUB);
    #pragma unroll 1
    for (int it = 0; it < 16; ++it) {
      int fi = it * 256 + tid;
      float4 v = cbq[fi];
      int k  = fi >> 3;
      int d0 = (fi & 7) * 4;
      int gg = d0 >> 3, e0 = d0 & 7;
      float vv[4] = {v.x, v.y, v.z, v.w};
      unsigned long long ph = 0ull, pl = 0ull;
      #pragma unroll
      for (int j = 0; j < 4; ++j) {
        unsigned short hh = bf16_rne(vv[j]);
        unsigned short ll = bf16_rne(__fsub_rn(vv[j], bf16_f32(hh)));
        ph |= ((unsigned long long)hh) << (16 * j);
        pl |= ((unsigned long long)ll) << (16 * j);
      }
      *(unsigned long long*)&s_cb[0][gg][k][e0] = ph;
      *(unsigned long long*)&s_cb[1][gg][k][e0] = pl;
    }
  }
  {
    const float4* z4 = (const float4*)z;
    #pragma unroll
    for (int it = 0; it < 2; ++it) {
      int fi = it * 256 + tid;
      int r = fi >> 3, j = fi & 7;
      float4 v = z4[(size_t)(row0 + r) * (EDIM / 4) + q * 8 + j];
      *(float4*)&s_z[r][j * 4] = v;
    }
  }
  if (tid < 128) ((float4*)s_cn)[tid] = ((const float4*)(cnorm + q * NE))[tid];
  __syncthreads();

  short8 ah, al;
  {
    const float* zr = &s_z[w * 16 + c16][g * 8];
    #pragma unroll
    for (int i = 0; i < 8; ++i) {
      float zv = zr[i];
      unsigned short hh = bf16_rne(zv);
      unsigned short ll = bf16_rne(__fsub_rn(zv, bf16_f32(hh)));
      ah[i] = (short)hh;
      al[i] = (short)ll;
    }
  }

  float v1[4] = {1e30f, 1e30f, 1e30f, 1e30f};
  float v2[4] = {1e30f, 1e30f, 1e30f, 1e30f};
  int   i1[4] = {0x7FFFFFFF, 0x7FFFFFFF, 0x7FFFFFFF, 0x7FFFFFFF};

  for (int ct = 0; ct < 32; ++ct) {
    int code = ct * 16 + c16;
    short8 bh = *(const short8*)&s_cb[0][g][code][0];
    short8 bl = *(const short8*)&s_cb[1][g][code][0];
    f32x4 acc = {0.f, 0.f, 0.f, 0.f};
    acc = __builtin_amdgcn_mfma_f32_16x16x32_bf16(ah, bh, acc, 0, 0, 0);
    acc = __builtin_amdgcn_mfma_f32_16x16x32_bf16(al, bh, acc, 0, 0, 0);
    acc = __builtin_amdgcn_mfma_f32_16x16x32_bf16(ah, bl, acc, 0, 0, 0);
    float cnv = s_cn[code];
    #pragma unroll
    for (int j = 0; j < 4; ++j) {
      float val = fmaf(-2.0f, acc[j], cnv);
      v2[j] = fminf(v2[j], fmaxf(v1[j], val));
      bool lt = val < v1[j];
      i1[j] = lt ? code : i1[j];
      v1[j] = fminf(v1[j], val);
    }
  }

  #pragma unroll
  for (int off = 1; off <= 8; off <<= 1) {
    #pragma unroll
    for (int j = 0; j < 4; ++j) {
      float ov1 = __shfl_xor(v1[j], off);
      float ov2 = __shfl_xor(v2[j], off);
      int   oi1 = __shfl_xor(i1[j], off);
      bool take = (ov1 < v1[j]) || (ov1 == v1[j] && oi1 < i1[j]);
      float loser = take ? v1[j] : ov1;
      v2[j] = fminf(fminf(v2[j], ov2), loser);
      v1[j] = take ? ov1 : v1[j];
      i1[j] = take ? oi1 : i1[j];
    }
  }
  #pragma unroll
  for (int j = 0; j < 4; ++j) {
    if (c16 == j) {
      unsigned int slow = (v2[j] <= v1[j] + MARGIN) ? 0x80000000u : 0u;
      s_res[w][g * 4 + j] = slow | (unsigned int)i1[j];
    }
  }

  for (int rr = 0; rr < 16; ++rr) {
    unsigned int resv = s_res[w][rr];
    if (resv & 0x80000000u) {
      int row_local = w * 16 + rr;
      const float* zrow = &s_z[row_local][0];
      float A = np_znorm32(zrow);
      float bv = 1e30f; int bk = 0x7FFFFFFF;
      #pragma unroll 2
      for (int i = 0; i < 8; ++i) {
        int k = lane * 8 + i;
        const float4* cp = (const float4*)(cb + ((size_t)(q * NE + k)) * DSUB);
        float ei = np_dot32(cp, zrow);
        float d2 = __fsub_rn(__fadd_rn(A, s_cn[k]), __fadd_rn(ei, ei));
        if (d2 < bv) { bv = d2; bk = k; }
      }
      #pragma unroll
      for (int off = 1; off <= 32; off <<= 1) {
        float ov = __shfl_xor(bv, off);
        int   ok = __shfl_xor(bk, off);
        if (ov < bv || (ov == bv && ok < bk)) { bv = ov; bk = ok; }
      }
      if (lane == 0) s_res[w][rr] = (unsigned int)bk;
    }
  }

  double lacc = 0.0;
  #pragma unroll
  for (int ii = 0; ii < 2; ++ii) {
    int rr = ii * 8 + (lane >> 3);
    int j8 = lane & 7;
    int row_local = w * 16 + rr;
    int n = row0 + row_local;
    int kstar = (int)(s_res[w][rr] & 0x7FFFFFFFu);
    float4 cv = ((const float4*)(cb + ((size_t)(q * NE + kstar)) * DSUB))[j8];
    *(float4*)(out_zq + (size_t)n * EDIM + q * DSUB + j8 * 4) = cv;
    const float* zp = &s_z[row_local][j8 * 4];
    double d0 = (double)cv.x - (double)zp[0];
    double d1 = (double)cv.y - (double)zp[1];
    double d2 = (double)cv.z - (double)zp[2];
    double d3 = (double)cv.w - (double)zp[3];
    lacc = fma(d0, d0, lacc); lacc = fma(d1, d1, lacc);
    lacc = fma(d2, d2, lacc); lacc = fma(d3, d3, lacc);
    if (j8 == 0) out_idx[(size_t)n * NQ + q] = (float)kstar;
  }

  #pragma unroll
  for (int off = 1; off < 64; off <<= 1) lacc += __shfl_xor(lacc, off);
  if (lane == 0) s_part[w] = lacc;
  __syncthreads();
  if (tid == 0)
    partials[blockIdx.y * gridDim.x + blockIdx.x] =
        (float)(s_part[0] + s_part[1] + s_part[2] + s_part[3]);
}

extern "C" void kernel_launch(void* const* d_in, const int* in_sizes, int n_in,
                              void* d_out, int out_size, void* d_ws, size_t ws_size,
                              hipStream_t stream) {
  const float* z  = (const float*)d_in[0];
  const float* cb = (const float*)d_in[1];
  float* out = (float*)d_out;
  float* out_zq   = out;
  float* out_loss = out + (size_t)NROWS * EDIM;
  float* out_idx  = out + (size_t)NROWS * EDIM + 1;

  // ws layout
  float* cnorm        = (float*)d_ws;                               // [0, 16K)
  float* cnh          = (float*)((char*)d_ws + 16384);              // [16K, 32K)
  float* partials     = (float*)((char*)d_ws + 32768);              // [32K, 40K)
  unsigned short* cbh = (unsigned short*)((char*)d_ws + 49152);     // [48K, 304K)
  unsigned short* cbl = (unsigned short*)((char*)d_ws + 49152 + 262144); // [304K, 560K)
  unsigned int* res   = (unsigned int*)((char*)d_ws + 49152 + 524288);  // [560K, 2.6M)

  const size_t ws_need = 49152 + 524288 + (size_t)NROWS * NQ * 4;

  vq_cnorm_kernel<<<NQ, 256, 0, stream>>>(cb, cnorm, cnh);
  if (ws_size >= ws_need) {
    vq_split_kernel<<<512, 256, 0, stream>>>(cb, cbh, cbl);
    dim3 grid(NROWS / RPB, NQ);
    vq_screen_kernel<<<grid, 256, 0, stream>>>(z, cbh, cbl, cnh, res);
    vq_gather_kernel<<<NROWS * NQ / 256, 256, 0, stream>>>(z, cb, cnorm, res,
                                                           out_zq, out_idx, partials);
    vq_loss_kernel<<<1, 256, 0, stream>>>(partials, NROWS * NQ / 256, out_loss);
  } else {
    dim3 grid(NROWS / RPB_FB, NQ);
    vq_mfma_fb_kernel<<<grid, 256, 0, stream>>>(z, cb, cnorm, out_zq, out_idx, partials);
    vq_loss_kernel<<<1, 256, 0, stream>>>(partials, (NROWS / RPB_FB) * NQ, out_loss);
  }
}

// Round 17
// 143.469 us; speedup vs baseline: 1.0617x; 1.0617x over previous
//
#include <hip/hip_runtime.h>

#define NROWS 65536
#define EDIM 256
#define NQ 8
#define NE 512
#define DSUB 32
#define RPB 128           // rows per screen block (2 row-groups of 16 per wave)
#define NRG 2             // row-groups per wave
#define RPB_FB 64         // fallback kernel rows per block
#define TILES 8
#define TCODES 64         // codes per LDS tile
#define MARGIN 1e-4f      // fallback kernel margin (r4-proven)
#define SM_ACC 7.5e-5f    // acc-scale screen margin (quant 3.05e-5 + 2*eps 2e-5)
#define KEYMASK 0xFFFFFE00u

typedef __attribute__((ext_vector_type(8))) short short8;
typedef __attribute__((ext_vector_type(4))) float f32x4;

#define GLOAD_LDS16(gp, lp)                                                  \
  __builtin_amdgcn_global_load_lds(                                          \
      (const __attribute__((address_space(1))) void*)(gp),                   \
      (__attribute__((address_space(3))) void*)(lp), 16, 0, 0)

// round-to-nearest-even f32 -> bf16 (bit-exact, deterministic)
static __device__ __forceinline__ unsigned short bf16_rne(float f) {
  unsigned int u = __float_as_uint(f);
  unsigned int r = 0x7FFFu + ((u >> 16) & 1u);
  return (unsigned short)((u + r) >> 16);
}
static __device__ __forceinline__ float bf16_f32(unsigned short h) {
  return __uint_as_float(((unsigned int)h) << 16);
}
static __device__ __forceinline__ unsigned int umed3(unsigned int a,
                                                     unsigned int b,
                                                     unsigned int c) {
  unsigned int d;
  asm("v_med3_u32 %0, %1, %2, %3" : "=v"(d) : "v"(a), "v"(b), "v"(c));
  return d;
}

// ===== numpy float32 bit-exact building blocks (validated rounds 3-16) =====
__device__ __forceinline__ float np_pairwise32(const float* p) {
  float r0 = p[0], r1 = p[1], r2 = p[2], r3 = p[3];
  float r4 = p[4], r5 = p[5], r6 = p[6], r7 = p[7];
  r0 = __fadd_rn(r0, p[8]);  r1 = __fadd_rn(r1, p[9]);
  r2 = __fadd_rn(r2, p[10]); r3 = __fadd_rn(r3, p[11]);
  r4 = __fadd_rn(r4, p[12]); r5 = __fadd_rn(r5, p[13]);
  r6 = __fadd_rn(r6, p[14]); r7 = __fadd_rn(r7, p[15]);
  r0 = __fadd_rn(r0, p[16]); r1 = __fadd_rn(r1, p[17]);
  r2 = __fadd_rn(r2, p[18]); r3 = __fadd_rn(r3, p[19]);
  r4 = __fadd_rn(r4, p[20]); r5 = __fadd_rn(r5, p[21]);
  r6 = __fadd_rn(r6, p[22]); r7 = __fadd_rn(r7, p[23]);
  r0 = __fadd_rn(r0, p[24]); r1 = __fadd_rn(r1, p[25]);
  r2 = __fadd_rn(r2, p[26]); r3 = __fadd_rn(r3, p[27]);
  r4 = __fadd_rn(r4, p[28]); r5 = __fadd_rn(r5, p[29]);
  r6 = __fadd_rn(r6, p[30]); r7 = __fadd_rn(r7, p[31]);
  float a = __fadd_rn(__fadd_rn(r0, r1), __fadd_rn(r2, r3));
  float b = __fadd_rn(__fadd_rn(r4, r5), __fadd_rn(r6, r7));
  return __fadd_rn(a, b);
}

// numpy pairwise ||z||^2, blockwise float4 (r6-proven order-preserving form)
__device__ __forceinline__ float np_znorm32(const float* zrow) {
  float r0, r1, r2, r3, r4, r5, r6, r7;
  float4 za = *(const float4*)&zrow[0];
  float4 zb = *(const float4*)&zrow[4];
  r0 = __fmul_rn(za.x, za.x); r1 = __fmul_rn(za.y, za.y);
  r2 = __fmul_rn(za.z, za.z); r3 = __fmul_rn(za.w, za.w);
  r4 = __fmul_rn(zb.x, zb.x); r5 = __fmul_rn(zb.y, zb.y);
  r6 = __fmul_rn(zb.z, zb.z); r7 = __fmul_rn(zb.w, zb.w);
  #pragma unroll
  for (int b = 1; b < 4; ++b) {
    za = *(const float4*)&zrow[b * 8];
    zb = *(const float4*)&zrow[b * 8 + 4];
    r0 = __fadd_rn(r0, __fmul_rn(za.x, za.x));
    r1 = __fadd_rn(r1, __fmul_rn(za.y, za.y));
    r2 = __fadd_rn(r2, __fmul_rn(za.z, za.z));
    r3 = __fadd_rn(r3, __fmul_rn(za.w, za.w));
    r4 = __fadd_rn(r4, __fmul_rn(zb.x, zb.x));
    r5 = __fadd_rn(r5, __fmul_rn(zb.y, zb.y));
    r6 = __fadd_rn(r6, __fmul_rn(zb.z, zb.z));
    r7 = __fadd_rn(r7, __fmul_rn(zb.w, zb.w));
  }
  float aa = __fadd_rn(__fadd_rn(r0, r1), __fadd_rn(r2, r3));
  float bb = __fadd_rn(__fadd_rn(r4, r5), __fadd_rn(r6, r7));
  return __fadd_rn(aa, bb);
}

// numpy einsum f32 dot over 32 dims (SSE blocks in order 3,2,1,0,7,6,5,4)
__device__ __forceinline__ float np_dot32(const float4* cp, const float* zrow) {
  float a0 = 0.f, a1 = 0.f, a2 = 0.f, a3 = 0.f;
  const int border[8] = {3, 2, 1, 0, 7, 6, 5, 4};
  #pragma unroll
  for (int bi = 0; bi < 8; ++bi) {
    int b = border[bi];
    float4 cv = cp[b];
    float4 zv = *(const float4*)&zrow[b * 4];
    a0 = __fadd_rn(__fmul_rn(cv.x, zv.x), a0);
    a1 = __fadd_rn(__fmul_rn(cv.y, zv.y), a1);
    a2 = __fadd_rn(__fmul_rn(cv.z, zv.z), a2);
    a3 = __fadd_rn(__fmul_rn(cv.w, zv.w), a3);
  }
  return __fadd_rn(__fadd_rn(a0, a1), __fadd_rn(a2, a3));
}

// exact numpy d2 for one (row, code)
__device__ __forceinline__ float np_d2(const float* __restrict__ cb,
                                       const float* __restrict__ cnorm,
                                       int q, int k, const float* zrow, float A) {
  const float4* cp = (const float4*)(cb + ((size_t)(q * NE + k)) * DSUB);
  float e = np_dot32(cp, zrow);
  return __fsub_rn(__fadd_rn(A, cnorm[q * NE + k]), __fadd_rn(e, e));
}

// ===== per-code squared norm (numpy semantics) + MFMA seed copy (-> ws) =====
// parallelized: 64 blocks x 64 threads, one code per thread (bit-identical math)
__global__ void vq_cnorm_kernel(const float* __restrict__ cb,
                                float* __restrict__ cnorm,
                                float* __restrict__ cnh) {
  int q = blockIdx.x;
  int k = blockIdx.y * 64 + threadIdx.x;
  const float* c = cb + ((size_t)(q * NE + k)) * DSUB;
  float p[DSUB];
  #pragma unroll
  for (int d = 0; d < DSUB; ++d) p[d] = __fmul_rn(c[d], c[d]);
  float s = np_pairwise32(p);
  cnorm[q * NE + k] = s;
  // MFMA accumulator seed: -(cn+1)/2  => acc = dot - (cn+1)/2, always < 0
  cnh[q * NE + k] = __fmul_rn(__fadd_rn(s, 1.0f), -0.5f);
}

// ===== pre-split codebook to bf16 hi/lo in LDS-tile order (-> ws) =====
__global__ void vq_split_kernel(const float* __restrict__ cb,
                                unsigned short* __restrict__ cbs) {
  int i = blockIdx.x * 256 + threadIdx.x;    // 0..131071
  float v = cb[i];
  unsigned short hh = bf16_rne(v);
  unsigned short ll = bf16_rne(__fsub_rn(v, bf16_f32(hh)));
  int d = i & 31;
  int k = (i >> 5) & 511;
  int q = i >> 14;
  int t = k >> 6, kk = k & 63, g = d >> 3, e = d & 7;
  size_t base = (size_t)q * 32768 + (size_t)t * 4096;
  cbs[base + (size_t)(g * TCODES + kk) * 8 + e] = hh;
  cbs[base + 2048 + (size_t)(g * TCODES + kk) * 8 + e] = ll;
}

// ===== stage A: MFMA screen, seeded-acc packed-key top-3 (r14-best) ====
// z fragments loaded DIRECTLY global->reg (no s_z): LDS 18 KB -> 8 blocks/CU
// res[n*8+q] = flag3<<31 | flag2<<30 | i2<<9 | i1
__global__ __launch_bounds__(256) void vq_screen_kernel(
    const float* __restrict__ z, const unsigned short* __restrict__ cbs,
    const float* __restrict__ cnh, unsigned int* __restrict__ res) {
  __shared__ unsigned short s_cbt[2][4096];   // 2 x 8 KB tile (hi 4KB + lo 4KB)
  __shared__ float s_cn[NE];                  // 2 KB (seed values)

  const int q    = blockIdx.y;
  const int row0 = blockIdx.x * RPB;
  const int tid  = threadIdx.x;
  const int w    = tid >> 6;
  const int lane = tid & 63;
  const int g    = lane >> 4;
  const int c16  = lane & 15;

  const unsigned short* cbq = cbs + (size_t)q * 32768;

  if (tid < 128) GLOAD_LDS16(cnh + q * NE + tid * 4, &s_cn[tid * 4]);
  #pragma unroll
  for (int it = 0; it < 2; ++it) {
    int off = it * 256 + tid;
    GLOAD_LDS16(cbq + off * 8, &s_cbt[0][off * 8]);
  }

  // A fragments: direct global->reg (each thread's own 2x8 z values)
  short8 ah0, al0, ah1, al1;
  {
    #pragma unroll
    for (int rg = 0; rg < 2; ++rg) {
      const float* zp = z + (size_t)(row0 + w * 32 + rg * 16 + c16) * EDIM
                          + q * DSUB + g * 8;
      float zr8[8];
      *(float4*)&zr8[0] = *(const float4*)&zp[0];
      *(float4*)&zr8[4] = *(const float4*)&zp[4];
      short8 h, l;
      #pragma unroll
      for (int i = 0; i < 8; ++i) {
        unsigned short hh = bf16_rne(zr8[i]);
        unsigned short ll = bf16_rne(__fsub_rn(zr8[i], bf16_f32(hh)));
        h[i] = (short)hh;
        l[i] = (short)ll;
      }
      if (rg == 0) { ah0 = h; al0 = l; } else { ah1 = h; al1 = l; }
    }
  }
  __syncthreads();   // cbt tile0 + cn resident

  // packed-key sorted triples per (rg, j): k1 <= k2 <= k3 (unsigned best-first;
  // acc always negative: smaller unsigned = larger acc = smaller d2)
  unsigned int k1[2][4], k2[2][4], k3[2][4];
  #pragma unroll
  for (int rg = 0; rg < 2; ++rg)
    #pragma unroll
    for (int j = 0; j < 4; ++j) {
      k1[rg][j] = 0xFFFFFFFFu; k2[rg][j] = 0xFFFFFFFFu; k3[rg][j] = 0xFFFFFFFFu;
    }

  int cur = 0;
  #pragma unroll 1
  for (int t = 0; t < TILES; ++t) {
    if (t < TILES - 1) {
      const unsigned short* src = cbq + (size_t)(t + 1) * 4096;
      #pragma unroll
      for (int it = 0; it < 2; ++it) {
        int off = it * 256 + tid;
        GLOAD_LDS16(src + off * 8, &s_cbt[cur ^ 1][off * 8]);
      }
    }
    #pragma unroll
    for (int ct2 = 0; ct2 < 4; ++ct2) {
      int kk = ct2 * 16 + c16;
      const unsigned short* bp = &s_cbt[cur][(g * TCODES + kk) * 8];
      short8 bh = *(const short8*)bp;
      short8 bl = *(const short8*)(bp + 2048);
      int code = t * TCODES + kk;
      float seed = s_cn[code];
      #pragma unroll
      for (int rg = 0; rg < 2; ++rg) {
        f32x4 acc = {seed, seed, seed, seed};  // acc = dot - (cn+1)/2 after MFMAs
        if (rg == 0) {
          acc = __builtin_amdgcn_mfma_f32_16x16x32_bf16(ah0, bh, acc, 0, 0, 0);
          acc = __builtin_amdgcn_mfma_f32_16x16x32_bf16(al0, bh, acc, 0, 0, 0);
          acc = __builtin_amdgcn_mfma_f32_16x16x32_bf16(ah0, bl, acc, 0, 0, 0);
        } else {
          acc = __builtin_amdgcn_mfma_f32_16x16x32_bf16(ah1, bh, acc, 0, 0, 0);
          acc = __builtin_amdgcn_mfma_f32_16x16x32_bf16(al1, bh, acc, 0, 0, 0);
          acc = __builtin_amdgcn_mfma_f32_16x16x32_bf16(ah1, bl, acc, 0, 0, 0);
        }
        #pragma unroll
        for (int j = 0; j < 4; ++j) {
          unsigned int key = (__float_as_uint(acc[j]) & KEYMASK) | (unsigned int)code;
          k3[rg][j] = umed3(k2[rg][j], k3[rg][j], key);
          k2[rg][j] = umed3(k1[rg][j], k2[rg][j], key);
          k1[rg][j] = min(k1[rg][j], key);
        }
      }
    }
    __syncthreads();
    cur ^= 1;
  }

  // cross-lane merge of sorted triples within each 16-lane group
  #pragma unroll
  for (int off = 1; off <= 8; off <<= 1) {
    #pragma unroll
    for (int rg = 0; rg < 2; ++rg)
      #pragma unroll
      for (int j = 0; j < 4; ++j) {
        unsigned int a1 = k1[rg][j], a2 = k2[rg][j], a3 = k3[rg][j];
        unsigned int b1 = (unsigned int)__shfl_xor((int)a1, off);
        unsigned int b2 = (unsigned int)__shfl_xor((int)a2, off);
        unsigned int b3 = (unsigned int)__shfl_xor((int)a3, off);
        unsigned int lo1 = min(a1, b1), hi1 = max(a1, b1);
        unsigned int lo2 = min(a2, b2), hi2 = max(a2, b2);
        unsigned int lo3 = min(a3, b3);
        k1[rg][j] = lo1;
        k2[rg][j] = min(hi1, lo2);
        k3[rg][j] = min(max(hi1, lo2), min(hi2, lo3));
      }
  }
  #pragma unroll
  for (int rg = 0; rg < 2; ++rg)
    #pragma unroll
    for (int j = 0; j < 4; ++j) {
      if (c16 == j) {
        float b1 = __uint_as_float(k1[rg][j] & KEYMASK);
        float b2 = __uint_as_float(k2[rg][j] & KEYMASK);
        float b3 = __uint_as_float(k3[rg][j] & KEYMASK);
        unsigned int u = (k1[rg][j] & 511u) | ((k2[rg][j] & 511u) << 9);
        if (__fsub_rn(b1, b2) <= SM_ACC) u |= (1u << 30);
        if (__fsub_rn(b1, b3) <= SM_ACC) u |= (1u << 31);
        res[(size_t)(row0 + w * 32 + rg * 16 + g * 4 + j) * NQ + q] = u;
      }
    }
}

// ===== stage B: gather + inline exact resolve + loss partials (r11) =====
__global__ __launch_bounds__(256) void vq_gather_kernel(
    const float* __restrict__ z, const float* __restrict__ cb,
    const float* __restrict__ cnorm, const unsigned int* __restrict__ res,
    float* __restrict__ out_zq, float* __restrict__ out_idx,
    float* __restrict__ partials) {
  __shared__ double s_part[4];
  const int e = blockIdx.x * 256 + threadIdx.x;
  const int n = e >> 3, q = e & 7;
  const int lane = threadIdx.x & 63;
  unsigned int u = res[e];
  int k = (int)(u & 511u);
  const float* zrow = z + (size_t)n * EDIM + q * DSUB;

  // 2-candidate exact numpy resolve (flag2 && !flag3)
  if ((u & 0x40000000u) && !(u & 0x80000000u)) {
    int k2 = (int)((u >> 9) & 511u);
    float A = np_znorm32(zrow);
    float d1 = np_d2(cb, cnorm, q, k,  zrow, A);
    float d2 = np_d2(cb, cnorm, q, k2, zrow, A);
    if (d2 < d1 || (d2 == d1 && k2 < k)) k = k2;
  }

  // rare flag3: wave-cooperative full numpy-exact rescan
  unsigned long long m = __ballot((u >> 31) & 1u);
  while (m) {
    int src = (int)__builtin_ctzll(m);
    m &= m - 1;
    int ee = blockIdx.x * 256 + (int)(threadIdx.x & ~63u) + src;  // wave-uniform
    int nn = ee >> 3, qq = ee & 7;
    const float* zr2 = z + (size_t)nn * EDIM + qq * DSUB;
    float A = np_znorm32(zr2);
    float bv = 1e30f; int bk = 0x7FFFFFFF;
    #pragma unroll 2
    for (int i = 0; i < 8; ++i) {
      int kk = lane * 8 + i;
      float d2 = np_d2(cb, cnorm, qq, kk, zr2, A);
      if (d2 < bv) { bv = d2; bk = kk; }     // ascending kk keeps lowest on tie
    }
    #pragma unroll
    for (int off = 1; off <= 32; off <<= 1) {
      float ov = __shfl_xor(bv, off);
      int   ok = __shfl_xor(bk, off);
      if (ov < bv || (ov == bv && ok < bk)) { bv = ov; bk = ok; }
    }
    if (lane == src) k = bk;
  }

  // outputs + f64 loss partial
  const float4* cp = (const float4*)(cb + ((size_t)(q * NE + k)) * DSUB);
  const float4* zp = (const float4*)zrow;
  float4* op = (float4*)(out_zq + (size_t)n * EDIM + q * DSUB);
  double lacc = 0.0;
  #pragma unroll
  for (int j = 0; j < 8; ++j) {
    float4 cv = cp[j];
    float4 zv = zp[j];
    op[j] = cv;
    double d0 = (double)cv.x - (double)zv.x;
    double d1 = (double)cv.y - (double)zv.y;
    double d2 = (double)cv.z - (double)zv.z;
    double d3 = (double)cv.w - (double)zv.w;
    lacc = fma(d0, d0, lacc); lacc = fma(d1, d1, lacc);
    lacc = fma(d2, d2, lacc); lacc = fma(d3, d3, lacc);
  }
  out_idx[e] = (float)k;

  const int w = threadIdx.x >> 6;
  #pragma unroll
  for (int off = 1; off < 64; off <<= 1) lacc += __shfl_xor(lacc, off);
  if (lane == 0) s_part[w] = lacc;
  __syncthreads();
  if (threadIdx.x == 0)
    partials[blockIdx.x] = (float)(s_part[0] + s_part[1] + s_part[2] + s_part[3]);
}

__global__ void vq_loss_kernel(const float* __restrict__ partials, int np,
                               float* __restrict__ out_loss) {
  __shared__ double sh[256];
  double s = 0.0;
  for (int i = threadIdx.x; i < np; i += 256) s += (double)partials[i];
  sh[threadIdx.x] = s;
  __syncthreads();
  for (int st = 128; st > 0; st >>= 1) {
    if ((int)threadIdx.x < st) sh[threadIdx.x] += sh[threadIdx.x + st];
    __syncthreads();
  }
  if (threadIdx.x == 0) {
    double m = sh[0] / 16777216.0;      // mean over 8*65536*32 elements
    *out_loss = (float)(1.25 * m);      // BETA*m + m
  }
}

// ===== fallback (round-4-style single kernel, known-passing) =====
__global__ __launch_bounds__(256) void vq_mfma_fb_kernel(
    const float* __restrict__ z, const float* __restrict__ cb,
    const float* __restrict__ cnorm,
    float* __restrict__ out_zq, float* __restrict__ out_idx,
    float* __restrict__ partials) {
  __shared__ unsigned short s_cb[2][4][NE][8];
  __shared__ float s_z[RPB_FB][DSUB];
  __shared__ float s_cn[NE];
  __shared__ unsigned int s_res[4][16];
  __shared__ double s_part[4];

  const int q    = blockIdx.y;
  const int row0 = blockIdx.x * RPB_FB;
  const int tid  = threadIdx.x;
  const int w    = tid >> 6;
  const int lane = tid & 63;
  const int g    = lane >> 4;
  const int c16  = lane & 15;

  {
    const float4* cbq = (const float4*)(cb + (size_t)q * NE * DSUB);
    #pragma unroll 1
    for (int it = 0; it < 16; ++it) {
      int fi = it * 256 + tid;
      float4 v = cbq[fi];
      int k  = fi >> 3;
      int d0 = (fi & 7) * 4;
      int gg = d0 >> 3, e0 = d0 & 7;
      float vv[4] = {v.x, v.y, v.z, v.w};
      unsigned long long ph = 0ull, pl = 0ull;
      #pragma unroll
      for (int j = 0; j < 4; ++j) {
        unsigned short hh = bf16_rne(vv[j]);
        unsigned short ll = bf16_rne(__fsub_rn(vv[j], bf16_f32(hh)));
        ph |= ((unsigned long long)hh) << (16 * j);
        pl |= ((unsigned long long)ll) << (16 * j);
      }
      *(unsigned long long*)&s_cb[0][gg][k][e0] = ph;
      *(unsigned long long*)&s_cb[1][gg][k][e0] = pl;
    }
  }
  {
    const float4* z4 = (const float4*)z;
    #pragma unroll
    for (int it = 0; it < 2; ++it) {
      int fi = it * 256 + tid;
      int r = fi >> 3, j = fi & 7;
      float4 v = z4[(size_t)(row0 + r) * (EDIM / 4) + q * 8 + j];
      *(float4*)&s_z[r][j * 4] = v;
    }
  }
  if (tid < 128) ((float4*)s_cn)[tid] = ((const float4*)(cnorm + q * NE))[tid];
  __syncthreads();

  short8 ah, al;
  {
    const float* zr = &s_z[w * 16 + c16][g * 8];
    #pragma unroll
    for (int i = 0; i < 8; ++i) {
      float zv = zr[i];
      unsigned short hh = bf16_rne(zv);
      unsigned short ll = bf16_rne(__fsub_rn(zv, bf16_f32(hh)));
      ah[i] = (short)hh;
      al[i] = (short)ll;
    }
  }

  float v1[4] = {1e30f, 1e30f, 1e30f, 1e30f};
  float v2[4] = {1e30f, 1e30f, 1e30f, 1e30f};
  int   i1[4] = {0x7FFFFFFF, 0x7FFFFFFF, 0x7FFFFFFF, 0x7FFFFFFF};

  for (int ct = 0; ct < 32; ++ct) {
    int code = ct * 16 + c16;
    short8 bh = *(const short8*)&s_cb[0][g][code][0];
    short8 bl = *(const short8*)&s_cb[1][g][code][0];
    f32x4 acc = {0.f, 0.f, 0.f, 0.f};
    acc = __builtin_amdgcn_mfma_f32_16x16x32_bf16(ah, bh, acc, 0, 0, 0);
    acc = __builtin_amdgcn_mfma_f32_16x16x32_bf16(al, bh, acc, 0, 0, 0);
    acc = __builtin_amdgcn_mfma_f32_16x16x32_bf16(ah, bl, acc, 0, 0, 0);
    float cnv = s_cn[code];
    #pragma unroll
    for (int j = 0; j < 4; ++j) {
      float val = fmaf(-2.0f, acc[j], cnv);
      v2[j] = fminf(v2[j], fmaxf(v1[j], val));
      bool lt = val < v1[j];
      i1[j] = lt ? code : i1[j];
      v1[j] = fminf(v1[j], val);
    }
  }

  #pragma unroll
  for (int off = 1; off <= 8; off <<= 1) {
    #pragma unroll
    for (int j = 0; j < 4; ++j) {
      float ov1 = __shfl_xor(v1[j], off);
      float ov2 = __shfl_xor(v2[j], off);
      int   oi1 = __shfl_xor(i1[j], off);
      bool take = (ov1 < v1[j]) || (ov1 == v1[j] && oi1 < i1[j]);
      float loser = take ? v1[j] : ov1;
      v2[j] = fminf(fminf(v2[j], ov2), loser);
      v1[j] = take ? ov1 : v1[j];
      i1[j] = take ? oi1 : i1[j];
    }
  }
  #pragma unroll
  for (int j = 0; j < 4; ++j) {
    if (c16 == j) {
      unsigned int slow = (v2[j] <= v1[j] + MARGIN) ? 0x80000000u : 0u;
      s_res[w][g * 4 + j] = slow | (unsigned int)i1[j];
    }
  }

  for (int rr = 0; rr < 16; ++rr) {
    unsigned int resv = s_res[w][rr];
    if (resv & 0x80000000u) {
      int row_local = w * 16 + rr;
      const float* zrow = &s_z[row_local][0];
      float A = np_znorm32(zrow);
      float bv = 1e30f; int bk = 0x7FFFFFFF;
      #pragma unroll 2
      for (int i = 0; i < 8; ++i) {
        int k = lane * 8 + i;
        const float4* cp = (const float4*)(cb + ((size_t)(q * NE + k)) * DSUB);
        float ei = np_dot32(cp, zrow);
        float d2 = __fsub_rn(__fadd_rn(A, s_cn[k]), __fadd_rn(ei, ei));
        if (d2 < bv) { bv = d2; bk = k; }
      }
      #pragma unroll
      for (int off = 1; off <= 32; off <<= 1) {
        float ov = __shfl_xor(bv, off);
        int   ok = __shfl_xor(bk, off);
        if (ov < bv || (ov == bv && ok < bk)) { bv = ov; bk = ok; }
      }
      if (lane == 0) s_res[w][rr] = (unsigned int)bk;
    }
  }

  double lacc = 0.0;
  #pragma unroll
  for (int ii = 0; ii < 2; ++ii) {
    int rr = ii * 8 + (lane >> 3);
    int j8 = lane & 7;
    int row_local = w * 16 + rr;
    int n = row0 + row_local;
    int kstar = (int)(s_res[w][rr] & 0x7FFFFFFFu);
    float4 cv = ((const float4*)(cb + ((size_t)(q * NE + kstar)) * DSUB))[j8];
    *(float4*)(out_zq + (size_t)n * EDIM + q * DSUB + j8 * 4) = cv;
    const float* zp = &s_z[row_local][j8 * 4];
    double d0 = (double)cv.x - (double)zp[0];
    double d1 = (double)cv.y - (double)zp[1];
    double d2 = (double)cv.z - (double)zp[2];
    double d3 = (double)cv.w - (double)zp[3];
    lacc = fma(d0, d0, lacc); lacc = fma(d1, d1, lacc);
    lacc = fma(d2, d2, lacc); lacc = fma(d3, d3, lacc);
    if (j8 == 0) out_idx[(size_t)n * NQ + q] = (float)kstar;
  }

  #pragma unroll
  for (int off = 1; off < 64; off <<= 1) lacc += __shfl_xor(lacc, off);
  if (lane == 0) s_part[w] = lacc;
  __syncthreads();
  if (tid == 0)
    partials[blockIdx.y * gridDim.x + blockIdx.x] =
        (float)(s_part[0] + s_part[1] + s_part[2] + s_part[3]);
}

extern "C" void kernel_launch(void* const* d_in, const int* in_sizes, int n_in,
                              void* d_out, int out_size, void* d_ws, size_t ws_size,
                              hipStream_t stream) {
  const float* z  = (const float*)d_in[0];
  const float* cb = (const float*)d_in[1];
  float* out = (float*)d_out;
  float* out_zq   = out;
  float* out_loss = out + (size_t)NROWS * EDIM;
  float* out_idx  = out + (size_t)NROWS * EDIM + 1;

  // ws layout: cnorm and cnh are each 4096 f32 = 16 KB
  float* cnorm        = (float*)d_ws;                               // [0, 16K)
  float* cnh          = (float*)((char*)d_ws + 16384);              // [16K, 32K)
  float* partials     = (float*)((char*)d_ws + 32768);              // [32K, 40K)
  unsigned short* cbs = (unsigned short*)((char*)d_ws + 49152);     // [48K, 560K)
  unsigned int* res   = (unsigned int*)((char*)d_ws + 49152 + 524288); // [560K, 2.6M)

  const size_t ws_need = 49152 + 524288 + (size_t)NROWS * NQ * 4;

  vq_cnorm_kernel<<<dim3(NQ, 8), 64, 0, stream>>>(cb, cnorm, cnh);
  if (ws_size >= ws_need) {
    vq_split_kernel<<<512, 256, 0, stream>>>(cb, cbs);
    dim3 grid(NROWS / RPB, NQ);
    vq_screen_kernel<<<grid, 256, 0, stream>>>(z, cbs, cnh, res);
    vq_gather_kernel<<<NROWS * NQ / 256, 256, 0, stream>>>(z, cb, cnorm, res,
                                                           out_zq, out_idx, partials);
    vq_loss_kernel<<<1, 256, 0, stream>>>(partials, NROWS * NQ / 256, out_loss);
  } else {
    dim3 grid(NROWS / RPB_FB, NQ);
    vq_mfma_fb_kernel<<<grid, 256, 0, stream>>>(z, cb, cnorm, out_zq, out_idx, partials);
    vq_loss_kernel<<<1, 256, 0, stream>>>(partials, (NROWS / RPB_FB) * NQ, out_loss);
  }
}